// Round 12
// baseline (182.405 us; speedup 1.0000x reference)
//
#include <hip/hip_runtime.h>

#define CIN 16
#define COUT 32
#define NB 8
#define HW 4096
#define PPW 66                 // padded image width
#define PPA (66 * 66)          // padded pixels per image
#define KF 160                 // features per pixel: 16ch * 10 (silu, T1..T8, zero)
#define NCH 20                 // 16B chunks per pixel (KF/8)

typedef short bf16x8 __attribute__((ext_vector_type(8)));
typedef float f32x4 __attribute__((ext_vector_type(4)));

__device__ inline unsigned short f2bf(float f) {
    unsigned u = __builtin_bit_cast(unsigned, f);
    u += 0x7FFFu + ((u >> 16) & 1u);            // RNE
    return (unsigned short)(u >> 16);
}
__device__ inline unsigned pk(float a, float b) {
    return (unsigned)f2bf(a) | ((unsigned)f2bf(b) << 16);
}

#define FEAT_N4 (16 * 4 * PPA)            // 278784 threads: (b, cg, pp), 4 channels each
#define FB4 ((FEAT_N4 + 255) / 256)       // 1089 blocks
#define WF_N (9 * COUT * KF)              // 46080 = 90 frags * 64 lanes * 8
#define WB ((WF_N + 255) / 256)           // 180 blocks
#define PH_FRAGS 30                       // 3 shifts * 10 frags per phase

// ---------- Prep (r8 body; gridDim.y replicates identical work for profiling) ----------
__global__ __launch_bounds__(256) void kan_prep(const float* __restrict__ x,
                                                const float* __restrict__ w,
                                                const float* __restrict__ c,
                                                unsigned short* __restrict__ g2t,
                                                unsigned short* __restrict__ wfl) {
    if (blockIdx.x < FB4) {
        const int t = blockIdx.x * 256 + threadIdx.x;
        if (t >= FEAT_N4) return;
        const int pp = t % PPA;
        const int bc = t / PPA;
        const int cg = bc & 3;
        const int b  = bc >> 2;
        const int py = pp / PPW;
        const int px = pp - py * PPW;

        unsigned rw[20];
        const bool interior = (py >= 1) & (py <= 64) & (px >= 1) & (px <= 64);
        if (interior) {
            const int pix = (py - 1) * 64 + (px - 1);
#pragma unroll
            for (int j = 0; j < 4; ++j) {
                const int i = cg * 4 + j;
                const float v  = x[((size_t)(b * CIN + i)) * HW + pix];
                const float p  = __expf(-v);
                const float p2 = p * p;
                const float s  = v * __builtin_amdgcn_rcpf(1.f + p);
                const float u  = (1.f - p2) * __builtin_amdgcn_rcpf(1.f + p2);
                const float u2 = 2.f * u;
                const float t1 = u;
                const float t2 = u2 * u - 1.f;
                const float t3 = u2 * t2 - t1;
                const float t4 = u2 * t3 - t2;
                const float t5 = u2 * t4 - t3;
                const float t6 = u2 * t5 - t4;
                const float t7 = u2 * t6 - t5;
                const float t8 = u2 * t7 - t6;
                rw[j * 5 + 0] = pk(s, t1);
                rw[j * 5 + 1] = pk(t2, t3);
                rw[j * 5 + 2] = pk(t4, t5);
                rw[j * 5 + 3] = pk(t6, t7);
                rw[j * 5 + 4] = (unsigned)f2bf(t8);
            }
        } else {
#pragma unroll
            for (int j = 0; j < 20; ++j) rw[j] = 0u;
        }
        uint4* dst = (uint4*)g2t;
#pragma unroll
        for (int q = 0; q < 5; ++q)
            dst[((size_t)(b * NCH + cg * 5 + q)) * PPA + pp] =
                make_uint4(rw[4 * q], rw[4 * q + 1], rw[4 * q + 2], rw[4 * q + 3]);
    } else {
        const int t = (blockIdx.x - FB4) * 256 + threadIdx.x;
        if (t >= WF_N) return;
        const int e    = t & 7;
        const int lane = (t >> 3) & 63;
        const int frag = t >> 9;              // 0..89 = (shift*5+st)*2 + f
        const int shift = frag / 10;
        const int r     = frag % 10;
        const int st    = r >> 1;
        const int f     = r & 1;
        const int o     = f * 16 + (lane & 15);
        const int kel   = st * 32 + (lane >> 4) * 8 + e;
        const int i     = kel / 10, n = kel % 10;
        float val = 0.f;
        if (n != 9) {
            const float wv = w[(size_t)(i * COUT + o) * 9 + shift];
            val = (n == 0) ? wv : wv * c[((size_t)(i * COUT + o) * 9 + shift) * NB + (n - 1)];
        }
        wfl[t] = f2bf(val);
    }
}

// ---------- GEMM ablation variants (r8 body) ----------
// V0 = full -> out.  V1 = no weight staging.  V2 = no B global loads.
// V3 = no A ds_reads (staging kept live via volatile LDS read).  V1-3 -> scratch.
template<int V>
__global__ __launch_bounds__(256, 4) void kan_gemm(const unsigned short* __restrict__ g2t,
                                                   const unsigned short* __restrict__ wfl,
                                                   float* __restrict__ out,
                                                   float* __restrict__ scratch) {
    __shared__ unsigned short ldsA[PH_FRAGS * 512];   // 30.7 KB

    const int bid = blockIdx.x;
    const int blk = ((bid & 7) << 7) | (bid >> 3);   // XCD swizzle
    const int b   = blk >> 6;
    const int y   = blk & 63;
    const int tid = threadIdx.x;
    const int l   = tid & 63;
    const int wv  = tid >> 6;
    const int col = l & 15;
    const int quad = l >> 4;
    const int x0  = wv * 16;

    const unsigned short* abase = ldsA + l * 8;

    f32x4 acc0 = {0.f, 0.f, 0.f, 0.f};
    f32x4 acc1 = {0.f, 0.f, 0.f, 0.f};

#pragma unroll
    for (int ph = 0; ph < 3; ++ph) {
        if (ph) __syncthreads();
        if constexpr (V != 1) {
            for (int ch = tid; ch < PH_FRAGS * 64; ch += 256)
                *(uint4*)&ldsA[ch * 8] = *(const uint4*)&wfl[((size_t)ph * PH_FRAGS * 64 + ch) * 8];
        }
        __syncthreads();

#pragma unroll
        for (int ls = 0; ls < 3; ++ls) {
            const int shift = ph * 3 + ls;
            const int dy = shift / 3 - 1, dx = shift % 3 - 1;
            const int pp = (y + 1 + dy) * PPW + (x0 + col + 1 + dx);
            const unsigned short* bq = g2t + (((size_t)b * NCH + quad) * PPA + pp) * 8;
#pragma unroll
            for (int st = 0; st < 5; ++st) {
                bf16x8 a0, a1, bf;
                if constexpr (V != 3) {
                    a0 = *(const bf16x8*)(abase + (ls * 10 + st * 2) * 512);
                    a1 = *(const bf16x8*)(abase + (ls * 10 + st * 2 + 1) * 512);
                }
                if constexpr (V != 2) bf = *(const bf16x8*)(bq + (size_t)st * 4 * PPA * 8);
                if constexpr (V == 2) bf = a0;
                if constexpr (V == 3) { a0 = bf; a1 = bf; }
                acc0 = __builtin_amdgcn_mfma_f32_16x16x32_bf16(a0, bf, acc0, 0, 0, 0);
                acc1 = __builtin_amdgcn_mfma_f32_16x16x32_bf16(a1, bf, acc1, 0, 0, 0);
            }
        }
    }

    if constexpr (V == 3) {   // keep staging stores alive (rule #17)
        unsigned short tmp = ((volatile unsigned short*)ldsA)[tid];
        asm volatile("" :: "v"((unsigned)tmp));
    }

    float* dst = (V == 0) ? out : scratch;
    float* op = dst + (size_t)b * COUT * HW + y * 64 + x0 + col;
#pragma unroll
    for (int r = 0; r < 4; ++r) {
        op[(size_t)(quad * 4 + r) * HW]      = acc0[r];
        op[(size_t)(quad * 4 + r + 16) * HW] = acc1[r];
    }
}

extern "C" void kernel_launch(void* const* d_in, const int* in_sizes, int n_in,
                              void* d_out, int out_size, void* d_ws, size_t ws_size,
                              hipStream_t stream) {
    const float* x = (const float*)d_in[0];
    const float* w = (const float*)d_in[1];
    const float* c = (const float*)d_in[2];
    float* out = (float*)d_out;

    unsigned short* g2t = (unsigned short*)d_ws;                       // 22.3 MB
    unsigned short* wfl = (unsigned short*)((char*)d_ws + (size_t)16 * PPA * KF * 2);
    float* scratch = (float*)((char*)d_ws + (size_t)32 * 1024 * 1024); // 8 MB at +32MB

    // Diagnostic: y-replication lifts kernels above harness fills in the profile.
    kan_prep<<<dim3(FB4 + WB, 8), 256, 0, stream>>>(x, w, c, g2t, wfl);
    kan_gemm<0><<<dim3(1024, 4), 256, 0, stream>>>(g2t, wfl, out, scratch);  // full (real out)
    kan_gemm<1><<<dim3(1024, 4), 256, 0, stream>>>(g2t, wfl, out, scratch);  // no staging
    kan_gemm<2><<<dim3(1024, 4), 256, 0, stream>>>(g2t, wfl, out, scratch);  // no B loads
    kan_gemm<3><<<dim3(1024, 4), 256, 0, stream>>>(g2t, wfl, out, scratch);  // no A ds_reads
}

// Round 13
// 140.687 us; speedup vs baseline: 1.2965x; 1.2965x over previous
//
#include <hip/hip_runtime.h>

#define CIN 16
#define COUT 32
#define NB 8
#define HW 4096
#define PPW 66                 // padded image width
#define PPA (66 * 66)          // padded pixels per image
#define KF 160                 // features per pixel: 16ch * 10 (silu, T1..T8, zero)
#define NCH 20                 // 16B chunks per pixel (KF/8)

typedef short bf16x8 __attribute__((ext_vector_type(8)));
typedef float f32x4 __attribute__((ext_vector_type(4)));

__device__ inline unsigned short f2bf(float f) {
    unsigned u = __builtin_bit_cast(unsigned, f);
    u += 0x7FFFu + ((u >> 16) & 1u);            // RNE
    return (unsigned short)(u >> 16);
}
__device__ inline unsigned pk(float a, float b) {
    return (unsigned)f2bf(a) | ((unsigned)f2bf(b) << 16);
}

#define WF_N (9 * COUT * KF)              // 46080 = 90 frags * 64 lanes * 8
#define PH_FRAGS 30                       // 3 shifts * 10 frags per phase
#define GRID_BLKS 1024

// Single fused kernel: phase 1 = features (XCD-local images) + weight fold;
// manual device-scope barrier (all 1024 blocks co-resident by construction:
// 4 blocks/CU * 256 CUs, VGPR<=128 via launch_bounds, LDS 30.7KB <= 40KB);
// phase 2 = r8's MFMA gemm. Block bid preps images {2*(bid&7), +1}; phase-2
// swizzle reads the same images -> g2t traffic stays in the XCD's L2.
__global__ __launch_bounds__(256, 4) void kan_fused(const float* __restrict__ x,
                                                    const float* __restrict__ w,
                                                    const float* __restrict__ c,
                                                    unsigned short* __restrict__ g2t,
                                                    unsigned short* __restrict__ wfl,
                                                    float* __restrict__ out,
                                                    unsigned* __restrict__ cnt) {
    __shared__ unsigned short ldsA[PH_FRAGS * 512];   // 30.7 KB

    const int bid = blockIdx.x;
    const int tid = threadIdx.x;
    const int xcd = bid & 7;
    const int jj  = bid >> 3;            // 0..127 within XCD group

    // ---- phase 1a: features for this XCD group's 2 images (8*PPA items) ----
    for (int t = jj * 256 + tid; t < 8 * PPA; t += 128 * 256) {
        const int pp = t % PPA;          // fastest -> coalesced stores
        const int q  = t / PPA;          // 0..7
        const int b  = 2 * xcd + (q >> 2);
        const int cg = q & 3;
        const int py = pp / PPW;
        const int px = pp - py * PPW;

        unsigned rw[20];
        const bool interior = (py >= 1) & (py <= 64) & (px >= 1) & (px <= 64);
        if (interior) {
            const int pix = (py - 1) * 64 + (px - 1);
#pragma unroll
            for (int j = 0; j < 4; ++j) {
                const int i = cg * 4 + j;
                const float v  = x[((size_t)(b * CIN + i)) * HW + pix];
                const float p  = __expf(-v);
                const float p2 = p * p;
                const float s  = v * __builtin_amdgcn_rcpf(1.f + p);           // silu
                const float u  = (1.f - p2) * __builtin_amdgcn_rcpf(1.f + p2); // tanh
                const float u2 = 2.f * u;
                const float t1 = u;
                const float t2 = u2 * u - 1.f;
                const float t3 = u2 * t2 - t1;
                const float t4 = u2 * t3 - t2;
                const float t5 = u2 * t4 - t3;
                const float t6 = u2 * t5 - t4;
                const float t7 = u2 * t6 - t5;
                const float t8 = u2 * t7 - t6;
                rw[j * 5 + 0] = pk(s, t1);
                rw[j * 5 + 1] = pk(t2, t3);
                rw[j * 5 + 2] = pk(t4, t5);
                rw[j * 5 + 3] = pk(t6, t7);
                rw[j * 5 + 4] = (unsigned)f2bf(t8);   // hi half 0 (pad feature)
            }
        } else {
#pragma unroll
            for (int j = 0; j < 20; ++j) rw[j] = 0u;
        }
        uint4* dst = (uint4*)g2t;
#pragma unroll
        for (int s5 = 0; s5 < 5; ++s5)
            dst[((size_t)(b * NCH + cg * 5 + s5)) * PPA + pp] =
                make_uint4(rw[4 * s5], rw[4 * s5 + 1], rw[4 * s5 + 2], rw[4 * s5 + 3]);
    }

    // ---- phase 1b: fragment-linear weight fold (first 180 blocks) ----
    if (bid < 180) {
        const int t = bid * 256 + tid;
        if (t < WF_N) {
            const int e    = t & 7;
            const int lane = (t >> 3) & 63;
            const int frag = t >> 9;          // 0..89 = (shift*5+st)*2 + f
            const int shift = frag / 10;
            const int r     = frag % 10;
            const int st    = r >> 1;
            const int f     = r & 1;
            const int o     = f * 16 + (lane & 15);
            const int kel   = st * 32 + (lane >> 4) * 8 + e;
            const int i     = kel / 10, n = kel % 10;
            float val = 0.f;
            if (n != 9) {
                const float wv = w[(size_t)(i * COUT + o) * 9 + shift];
                val = (n == 0) ? wv : wv * c[((size_t)(i * COUT + o) * 9 + shift) * NB + (n - 1)];
            }
            wfl[t] = f2bf(val);
        }
    }

    // ---- grid barrier: device-scope release/acquire (cross-XCD safe) ----
    __syncthreads();
    if (tid == 0) {
        __hip_atomic_fetch_add(cnt, 1u, __ATOMIC_RELEASE, __HIP_MEMORY_SCOPE_AGENT);
        while (__hip_atomic_load(cnt, __ATOMIC_ACQUIRE, __HIP_MEMORY_SCOPE_AGENT) < GRID_BLKS)
            __builtin_amdgcn_s_sleep(1);
    }
    __syncthreads();

    // ---- phase 2: MFMA GEMM (r8 body) ----
    const int blk = ((bid & 7) << 7) | (bid >> 3);   // same images as phase 1a
    const int b   = blk >> 6;
    const int y   = blk & 63;
    const int l   = tid & 63;
    const int wv  = tid >> 6;
    const int col = l & 15;
    const int quad = l >> 4;
    const int x0  = wv * 16;

    const unsigned short* abase = ldsA + l * 8;   // lane-linear A reads (conflict-free)

    f32x4 acc0 = {0.f, 0.f, 0.f, 0.f};
    f32x4 acc1 = {0.f, 0.f, 0.f, 0.f};

#pragma unroll
    for (int ph = 0; ph < 3; ++ph) {
        if (ph) __syncthreads();
        for (int ch = tid; ch < PH_FRAGS * 64; ch += 256)
            *(uint4*)&ldsA[ch * 8] = *(const uint4*)&wfl[((size_t)ph * PH_FRAGS * 64 + ch) * 8];
        __syncthreads();

#pragma unroll
        for (int ls = 0; ls < 3; ++ls) {
            const int shift = ph * 3 + ls;
            const int dy = shift / 3 - 1, dx = shift % 3 - 1;
            const int pp = (y + 1 + dy) * PPW + (x0 + col + 1 + dx);
            // chunk-major B: chunk = st*4 + quad, lanes 0-15 consecutive pp
            const unsigned short* bq = g2t + (((size_t)b * NCH + quad) * PPA + pp) * 8;
#pragma unroll
            for (int st = 0; st < 5; ++st) {
                const bf16x8 bf = *(const bf16x8*)(bq + (size_t)st * 4 * PPA * 8);
                const bf16x8 a0 = *(const bf16x8*)(abase + (ls * 10 + st * 2) * 512);
                const bf16x8 a1 = *(const bf16x8*)(abase + (ls * 10 + st * 2 + 1) * 512);
                acc0 = __builtin_amdgcn_mfma_f32_16x16x32_bf16(a0, bf, acc0, 0, 0, 0);
                acc1 = __builtin_amdgcn_mfma_f32_16x16x32_bf16(a1, bf, acc1, 0, 0, 0);
            }
        }
    }

    float* op = out + (size_t)b * COUT * HW + y * 64 + x0 + col;
#pragma unroll
    for (int r = 0; r < 4; ++r) {
        op[(size_t)(quad * 4 + r) * HW]      = acc0[r];
        op[(size_t)(quad * 4 + r + 16) * HW] = acc1[r];
    }
}

extern "C" void kernel_launch(void* const* d_in, const int* in_sizes, int n_in,
                              void* d_out, int out_size, void* d_ws, size_t ws_size,
                              hipStream_t stream) {
    const float* x = (const float*)d_in[0];
    const float* w = (const float*)d_in[1];
    const float* c = (const float*)d_in[2];
    float* out = (float*)d_out;

    unsigned short* g2t = (unsigned short*)d_ws;                       // 22.3 MB
    unsigned short* wfl = (unsigned short*)((char*)d_ws + (size_t)16 * PPA * KF * 2);
    unsigned* cnt = (unsigned*)((char*)d_ws + (size_t)23 * 1024 * 1024);

    hipMemsetAsync(cnt, 0, 4, stream);
    kan_fused<<<GRID_BLKS, 256, 0, stream>>>(x, w, c, g2t, wfl, out, cnt);
}

// Round 14
// 40.602 us; speedup vs baseline: 4.4925x; 3.4651x over previous
//
#include <hip/hip_runtime.h>

#define CIN 16
#define COUT 32
#define NB 8
#define HW 4096
#define PPW 66                 // padded image width
#define PPA (66 * 66)          // padded pixels per image
#define KF 160                 // features per pixel: 16ch * 10 (silu, T1..T8, zero)
#define NCH 20                 // 16B chunks per pixel (KF/8)

typedef short bf16x8 __attribute__((ext_vector_type(8)));
typedef float f32x4 __attribute__((ext_vector_type(4)));

__device__ inline unsigned short f2bf(float f) {
    unsigned u = __builtin_bit_cast(unsigned, f);
    u += 0x7FFFu + ((u >> 16) & 1u);            // RNE
    return (unsigned short)(u >> 16);
}
__device__ inline unsigned pk(float a, float b) {
    return (unsigned)f2bf(a) | ((unsigned)f2bf(b) << 16);
}

#define FEAT_N4 (16 * 4 * PPA)            // 278784 threads: (b, cg, pp), 4 channels each
#define FB4 ((FEAT_N4 + 255) / 256)       // 1089 blocks
#define WF_N (9 * COUT * KF)              // 46080 = 90 frags * 64 lanes * 8
#define WB ((WF_N + 255) / 256)           // 180 blocks

// ---------- Prep: features chunk-major g2t[b][c][pp][8] + fragment-linear weights ----------
// wfl: frag = (shift*5 + st)*2 + f; wfl[frag*512 + lane*8 + e] =
//   Wf[shift][o = f*16 + (lane&15)][kel = st*32 + (lane>>4)*8 + e]
__global__ __launch_bounds__(256) void kan_prep(const float* __restrict__ x,
                                                const float* __restrict__ w,
                                                const float* __restrict__ c,
                                                unsigned short* __restrict__ g2t,
                                                unsigned short* __restrict__ wfl) {
    if (blockIdx.x < FB4) {
        const int t = blockIdx.x * 256 + threadIdx.x;
        if (t >= FEAT_N4) return;
        const int pp = t % PPA;           // fastest -> coalesced stores
        const int bc = t / PPA;
        const int cg = bc & 3;
        const int b  = bc >> 2;
        const int py = pp / PPW;
        const int px = pp - py * PPW;

        unsigned rw[20];
        const bool interior = (py >= 1) & (py <= 64) & (px >= 1) & (px <= 64);
        if (interior) {
            const int pix = (py - 1) * 64 + (px - 1);
#pragma unroll
            for (int j = 0; j < 4; ++j) {
                const int i = cg * 4 + j;
                const float v  = x[((size_t)(b * CIN + i)) * HW + pix];
                const float p  = __expf(-v);
                const float p2 = p * p;
                const float s  = v * __builtin_amdgcn_rcpf(1.f + p);           // silu
                const float u  = (1.f - p2) * __builtin_amdgcn_rcpf(1.f + p2); // tanh
                const float u2 = 2.f * u;
                const float t1 = u;
                const float t2 = u2 * u - 1.f;
                const float t3 = u2 * t2 - t1;
                const float t4 = u2 * t3 - t2;
                const float t5 = u2 * t4 - t3;
                const float t6 = u2 * t5 - t4;
                const float t7 = u2 * t6 - t5;
                const float t8 = u2 * t7 - t6;
                rw[j * 5 + 0] = pk(s, t1);
                rw[j * 5 + 1] = pk(t2, t3);
                rw[j * 5 + 2] = pk(t4, t5);
                rw[j * 5 + 3] = pk(t6, t7);
                rw[j * 5 + 4] = (unsigned)f2bf(t8);   // hi half 0 (pad feature)
            }
        } else {
#pragma unroll
            for (int j = 0; j < 20; ++j) rw[j] = 0u;
        }
        uint4* dst = (uint4*)g2t;
#pragma unroll
        for (int q = 0; q < 5; ++q)
            dst[((size_t)(b * NCH + cg * 5 + q)) * PPA + pp] =
                make_uint4(rw[4 * q], rw[4 * q + 1], rw[4 * q + 2], rw[4 * q + 3]);
    } else {
        const int t = (blockIdx.x - FB4) * 256 + threadIdx.x;
        if (t >= WF_N) return;
        const int e    = t & 7;
        const int lane = (t >> 3) & 63;
        const int frag = t >> 9;              // 0..89 = (shift*5+st)*2 + f
        const int shift = frag / 10;
        const int r     = frag % 10;
        const int st    = r >> 1;
        const int f     = r & 1;
        const int o     = f * 16 + (lane & 15);
        const int kel   = st * 32 + (lane >> 4) * 8 + e;
        const int i     = kel / 10, n = kel % 10;
        float val = 0.f;
        if (n != 9) {
            const float wv = w[(size_t)(i * COUT + o) * 9 + shift];
            val = (n == 0) ? wv : wv * c[((size_t)(i * COUT + o) * 9 + shift) * NB + (n - 1)];
        }
        wfl[t] = f2bf(val);
    }
}

// ---------- MFMA GEMM: no LDS, no barriers; A fragment-linear from global (L1/L2-hot) ----------
// Block = 4 waves = one image row (b,y); wave wv owns 16 px, all 32 cout.
// A-load: wfl + frag*1024B + lane*16B -> coalesced 1KB, 16 cache lines (vs r4's 64).
__global__ __launch_bounds__(256) void kan_gemm(const unsigned short* __restrict__ g2t,
                                                const unsigned short* __restrict__ wfl,
                                                float* __restrict__ out) {
    const int bid = blockIdx.x;
    const int blk = ((bid & 7) << 7) | (bid >> 3);   // XCD swizzle: 2 images per XCD
    const int b   = blk >> 6;
    const int y   = blk & 63;
    const int tid = threadIdx.x;
    const int l   = tid & 63;
    const int wv  = tid >> 6;
    const int col = l & 15;
    const int quad = l >> 4;
    const int x0  = wv * 16;

    const unsigned short* abase = wfl + l * 8;    // lane-linear A reads from global

    f32x4 acc0 = {0.f, 0.f, 0.f, 0.f};
    f32x4 acc1 = {0.f, 0.f, 0.f, 0.f};

#pragma unroll
    for (int shift = 0; shift < 9; ++shift) {
        const int dy = shift / 3 - 1, dx = shift % 3 - 1;
        const int pp = (y + 1 + dy) * PPW + (x0 + col + 1 + dx);
        // chunk-major B: chunk = st*4 + quad, lanes 0-15 consecutive pp
        const unsigned short* bq = g2t + (((size_t)b * NCH + quad) * PPA + pp) * 8;
#pragma unroll
        for (int st = 0; st < 5; ++st) {
            const bf16x8 bf = *(const bf16x8*)(bq + (size_t)st * 4 * PPA * 8);
            const bf16x8 a0 = *(const bf16x8*)(abase + ((shift * 5 + st) * 2) * 512);
            const bf16x8 a1 = *(const bf16x8*)(abase + ((shift * 5 + st) * 2 + 1) * 512);
            acc0 = __builtin_amdgcn_mfma_f32_16x16x32_bf16(a0, bf, acc0, 0, 0, 0);
            acc1 = __builtin_amdgcn_mfma_f32_16x16x32_bf16(a1, bf, acc1, 0, 0, 0);
        }
    }

    float* op = out + (size_t)b * COUT * HW + y * 64 + x0 + col;
#pragma unroll
    for (int r = 0; r < 4; ++r) {
        op[(size_t)(quad * 4 + r) * HW]      = acc0[r];
        op[(size_t)(quad * 4 + r + 16) * HW] = acc1[r];
    }
}

extern "C" void kernel_launch(void* const* d_in, const int* in_sizes, int n_in,
                              void* d_out, int out_size, void* d_ws, size_t ws_size,
                              hipStream_t stream) {
    const float* x = (const float*)d_in[0];
    const float* w = (const float*)d_in[1];
    const float* c = (const float*)d_in[2];
    float* out = (float*)d_out;

    unsigned short* g2t = (unsigned short*)d_ws;                       // 22.3 MB
    unsigned short* wfl = (unsigned short*)((char*)d_ws + (size_t)16 * PPA * KF * 2);

    kan_prep<<<FB4 + WB, 256, 0, stream>>>(x, w, c, g2t, wfl);
    kan_gemm<<<1024, 256, 0, stream>>>(g2t, wfl, out);
}

// Round 15
// 33.731 us; speedup vs baseline: 5.4077x; 1.2037x over previous
//
#include <hip/hip_runtime.h>

#define CIN 16
#define COUT 32
#define NB 8
#define HW 4096
#define PPW 66                 // padded image width
#define PPA (66 * 66)          // padded pixels per image
#define KF 160                 // features per pixel: 16ch * 10 (silu, T1..T8, zero)
#define NCH 20                 // 16B chunks per pixel (KF/8)

typedef short bf16x8 __attribute__((ext_vector_type(8)));
typedef float f32x4 __attribute__((ext_vector_type(4)));

__device__ inline unsigned short f2bf(float f) {
    unsigned u = __builtin_bit_cast(unsigned, f);
    u += 0x7FFFu + ((u >> 16) & 1u);            // RNE
    return (unsigned short)(u >> 16);
}
__device__ inline unsigned pk(float a, float b) {
    return (unsigned)f2bf(a) | ((unsigned)f2bf(b) << 16);
}

#define FEAT_N4 (16 * 4 * PPA)            // 278784 threads: (b, cg, pp), 4 channels each
#define FB4 ((FEAT_N4 + 255) / 256)       // 1089 blocks
#define WF_N (9 * COUT * KF)              // 46080 = 90 frags * 64 lanes * 8
#define WB ((WF_N + 255) / 256)           // 180 blocks

// ---------- Prep: features chunk-major g2t[b][c][pp][8] + fragment-linear weights ----------
// wfl: frag = (shift*5 + st)*2 + f; wfl[frag*512 + lane*8 + e] =
//   Wf[shift][o = f*16 + (lane&15)][kel = st*32 + (lane>>4)*8 + e]
__global__ __launch_bounds__(256) void kan_prep(const float* __restrict__ x,
                                                const float* __restrict__ w,
                                                const float* __restrict__ c,
                                                unsigned short* __restrict__ g2t,
                                                unsigned short* __restrict__ wfl) {
    if (blockIdx.x < FB4) {
        const int t = blockIdx.x * 256 + threadIdx.x;
        if (t >= FEAT_N4) return;
        const int pp = t % PPA;           // fastest -> coalesced stores
        const int bc = t / PPA;
        const int cg = bc & 3;
        const int b  = bc >> 2;
        const int py = pp / PPW;
        const int px = pp - py * PPW;

        unsigned rw[20];
        const bool interior = (py >= 1) & (py <= 64) & (px >= 1) & (px <= 64);
        if (interior) {
            const int pix = (py - 1) * 64 + (px - 1);
#pragma unroll
            for (int j = 0; j < 4; ++j) {
                const int i = cg * 4 + j;
                const float v  = x[((size_t)(b * CIN + i)) * HW + pix];
                const float p  = __expf(-v);
                const float p2 = p * p;
                const float s  = v * __builtin_amdgcn_rcpf(1.f + p);           // silu
                const float u  = (1.f - p2) * __builtin_amdgcn_rcpf(1.f + p2); // tanh
                const float u2 = 2.f * u;
                const float t1 = u;
                const float t2 = u2 * u - 1.f;
                const float t3 = u2 * t2 - t1;
                const float t4 = u2 * t3 - t2;
                const float t5 = u2 * t4 - t3;
                const float t6 = u2 * t5 - t4;
                const float t7 = u2 * t6 - t5;
                const float t8 = u2 * t7 - t6;
                rw[j * 5 + 0] = pk(s, t1);
                rw[j * 5 + 1] = pk(t2, t3);
                rw[j * 5 + 2] = pk(t4, t5);
                rw[j * 5 + 3] = pk(t6, t7);
                rw[j * 5 + 4] = (unsigned)f2bf(t8);   // hi half 0 (pad feature)
            }
        } else {
#pragma unroll
            for (int j = 0; j < 20; ++j) rw[j] = 0u;
        }
        uint4* dst = (uint4*)g2t;
#pragma unroll
        for (int q = 0; q < 5; ++q)
            dst[((size_t)(b * NCH + cg * 5 + q)) * PPA + pp] =
                make_uint4(rw[4 * q], rw[4 * q + 1], rw[4 * q + 2], rw[4 * q + 3]);
    } else {
        const int t = (blockIdx.x - FB4) * 256 + threadIdx.x;
        if (t >= WF_N) return;
        const int e    = t & 7;
        const int lane = (t >> 3) & 63;
        const int frag = t >> 9;              // 0..89 = (shift*5+st)*2 + f
        const int shift = frag / 10;
        const int r     = frag % 10;
        const int st    = r >> 1;
        const int f     = r & 1;
        const int o     = f * 16 + (lane & 15);
        const int kel   = st * 32 + (lane >> 4) * 8 + e;
        const int i     = kel / 10, n = kel % 10;
        float val = 0.f;
        if (n != 9) {
            const float wv = w[(size_t)(i * COUT + o) * 9 + shift];
            val = (n == 0) ? wv : wv * c[((size_t)(i * COUT + o) * 9 + shift) * NB + (n - 1)];
        }
        wfl[t] = f2bf(val);
    }
}

// ---------- MFMA GEMM: single 92KB stage, ONE barrier, free-running 45-iter waves ----------
// 256 blocks x 1024 thr = 1 block/CU, 16 waves/CU. Block = 4 rows x 4 waves;
// wave = 16 px x 32 cout. All 90 weight frags in dynamic LDS (fragment-linear).
#define GEMM_LDS_BYTES (90 * 512 * 2)      // 92160 B

__global__ __launch_bounds__(1024, 4) void kan_gemm(const unsigned short* __restrict__ g2t,
                                                    const unsigned short* __restrict__ wfl,
                                                    float* __restrict__ out) {
    extern __shared__ __align__(16) unsigned short ldsA[];

    const int bid = blockIdx.x;
    const int blk = ((bid & 7) << 5) | (bid >> 3);   // XCD x gets images {2x, 2x+1}
    const int b   = blk >> 4;
    const int rg  = blk & 15;            // row group: rows rg*4 .. rg*4+3
    const int tid = threadIdx.x;
    const int l   = tid & 63;
    const int wv  = tid >> 6;            // 0..15
    const int y   = rg * 4 + (wv >> 2);
    const int x0  = (wv & 3) * 16;
    const int col = l & 15;
    const int quad = l >> 4;

    // one-shot stage: 5760 x 16B, coalesced
    for (int ch = tid; ch < 90 * 64; ch += 1024)
        *(uint4*)&ldsA[ch * 8] = *(const uint4*)&wfl[ch * 8];
    __syncthreads();                     // the ONLY barrier

    const unsigned short* abase = ldsA + l * 8;   // lane-linear A reads (conflict-free)

    f32x4 acc0 = {0.f, 0.f, 0.f, 0.f};
    f32x4 acc1 = {0.f, 0.f, 0.f, 0.f};

#pragma unroll
    for (int shift = 0; shift < 9; ++shift) {
        const int dy = shift / 3 - 1, dx = shift % 3 - 1;
        const int pp = (y + 1 + dy) * PPW + (x0 + col + 1 + dx);
        // chunk-major B: chunk = st*4 + quad, lanes 0-15 consecutive pp
        const unsigned short* bq = g2t + (((size_t)b * NCH + quad) * PPA + pp) * 8;
#pragma unroll
        for (int st = 0; st < 5; ++st) {
            const bf16x8 bf = *(const bf16x8*)(bq + (size_t)st * 4 * PPA * 8);
            const bf16x8 a0 = *(const bf16x8*)(abase + ((shift * 5 + st) * 2) * 512);
            const bf16x8 a1 = *(const bf16x8*)(abase + ((shift * 5 + st) * 2 + 1) * 512);
            acc0 = __builtin_amdgcn_mfma_f32_16x16x32_bf16(a0, bf, acc0, 0, 0, 0);
            acc1 = __builtin_amdgcn_mfma_f32_16x16x32_bf16(a1, bf, acc1, 0, 0, 0);
        }
    }

    float* op = out + (size_t)b * COUT * HW + y * 64 + x0 + col;
#pragma unroll
    for (int r = 0; r < 4; ++r) {
        op[(size_t)(quad * 4 + r) * HW]      = acc0[r];
        op[(size_t)(quad * 4 + r + 16) * HW] = acc1[r];
    }
}

extern "C" void kernel_launch(void* const* d_in, const int* in_sizes, int n_in,
                              void* d_out, int out_size, void* d_ws, size_t ws_size,
                              hipStream_t stream) {
    const float* x = (const float*)d_in[0];
    const float* w = (const float*)d_in[1];
    const float* c = (const float*)d_in[2];
    float* out = (float*)d_out;

    unsigned short* g2t = (unsigned short*)d_ws;                       // 22.3 MB
    unsigned short* wfl = (unsigned short*)((char*)d_ws + (size_t)16 * PPA * KF * 2);

    // allow >64KB dynamic LDS (gfx950 supports up to 160KB/WG); host-side, capture-safe
    hipFuncSetAttribute((const void*)kan_gemm,
                        hipFuncAttributeMaxDynamicSharedMemorySize, GEMM_LDS_BYTES);

    kan_prep<<<FB4 + WB, 256, 0, stream>>>(x, w, c, g2t, wfl);
    kan_gemm<<<256, 1024, GEMM_LDS_BYTES, stream>>>(g2t, wfl, out);
}